// Round 5
// baseline (1292.500 us; speedup 1.0000x reference)
//
#include <hip/hip_runtime.h>
#include <cstdint>
#include <cstddef>

// ---------------- problem constants ----------------
#define N_B   4
#define L_Q   4096
#define S_K   4096
#define H_N   8
#define E_D   64
#define D_V   64
#define C_C   256
#define NBITS 32
#define KITERS 10
#define NH    32            // N_B*H_N
#define NCHUNK 8
#define CHUNK  512          // keys per attention chunk

typedef __attribute__((ext_vector_type(4))) float f32x4;

#define TS_CONST (0.125f * 1.44269504088896340736f)   // softmax_temp * log2(e)

// ---------------- kernel 1: LSH bits ----------------
// thread per (nh,l); f64 accumulation (matches any f64-ordered np reference
// to ~1e-13; sign-flip probability ~1e-9 per bit).
__global__ __launch_bounds__(256) void k_bits(const float* __restrict__ q,
                                              const float* __restrict__ planes,
                                              unsigned* __restrict__ bits_g) {
  __shared__ float pl[NBITS][E_D + 1];
  int tid = threadIdx.x;
  for (int i = tid; i < NBITS * (E_D + 1); i += 256) pl[i / (E_D+1)][i % (E_D+1)] = planes[i];
  __syncthreads();
  int l  = blockIdx.x * 256 + tid;
  int nh = blockIdx.y;
  int n = nh >> 3, h = nh & 7;
  const float* qp = q + ((size_t)((size_t)(n * L_Q + l) * H_N + h)) * E_D;
  float qv[E_D];
#pragma unroll
  for (int j = 0; j < E_D/4; ++j) {
    f32x4 v = *(const f32x4*)(qp + 4*j);
    qv[4*j+0] = v[0]; qv[4*j+1] = v[1]; qv[4*j+2] = v[2]; qv[4*j+3] = v[3];
  }
  unsigned w = 0;
#pragma unroll
  for (int half = 0; half < 2; ++half) {
    double acc[NBITS/2];
#pragma unroll
    for (int b = 0; b < NBITS/2; ++b) acc[b] = 0.0;
#pragma unroll 4
    for (int e = 0; e < E_D; ++e) {
      double qe = (double)qv[e];
#pragma unroll
      for (int b = 0; b < NBITS/2; ++b)
        acc[b] = fma(qe, (double)pl[half*(NBITS/2) + b][e], acc[b]);
    }
#pragma unroll
    for (int b = 0; b < NBITS/2; ++b) {
      double p = acc[b] + (double)pl[half*(NBITS/2) + b][E_D];
      if (p > 0.0) w |= (1u << (half*(NBITS/2) + b));
    }
  }
  bits_g[(size_t)nh * L_Q + l] = w;
}

// ---------------- kernel 2: Lloyd clustering + Qg (f32 out) ----------------
// one workgroup (512 thr) per nh. Exact integer popcount argmin:
//   key = (popc(x ^ cent_c) << 8) | c ; min == first-min argmin (matches np.argmin).
// LDS layout (bytes):
//   sums64 : 0      .. 16384   u64[256][8]  (4x16-bit packed bit counters)
//   bitsL  : 16384  .. 32768   u32[4096]
//   assignL: 32768  .. 49152   u32[4096]
//   centL  : 49152  .. 50176   u32[256]
//   countsL: 51200  .. 52224   u32[256]
//   qgL    : 52224  .. 118784  f32[256][65]
__global__ __launch_bounds__(512) void k_cluster(const unsigned* __restrict__ bits_g,
                                                 const float* __restrict__ q,
                                                 unsigned* __restrict__ assign_g,
                                                 float* __restrict__ qg_f32) {
  extern __shared__ char smem[];
  unsigned long long* sums64 = (unsigned long long*)smem;
  unsigned* bitsL   = (unsigned*)(smem + 16384);
  unsigned* assignL = (unsigned*)(smem + 32768);
  unsigned* centL   = (unsigned*)(smem + 49152);
  unsigned* countsL = (unsigned*)(smem + 51200);
  float*    qgL     = (float*)(smem + 52224);

  int tid = threadIdx.x, nh = blockIdx.x;

  for (int r = tid; r < L_Q; r += 512) bitsL[r] = bits_g[(size_t)nh * L_Q + r];
  __syncthreads();
  if (tid < C_C) {
    // np.linspace(0, 4095, 256) computed in FLOAT64 (ref=np), truncated:
    // idx[i] = floor(i*(16+1/17)) = 16*i + i/17 EXACTLY for all i
    // (f64 product error k*2^-48 always < half-ulp of 273k; endpoint
    // 255 -> 4080+15 = 4095 needs no special case).
    // NOTE: the f32 (jnp) variant differs at 10 indices (i=51,85,102,...):
    // that mismatch was the sole source of the 4.6e-2 absmax plateau.
    centL[tid] = bitsL[tid * 16 + tid / 17];
  }
  __syncthreads();

  for (int it = 0; it <= KITERS; ++it) {
    bool last = (it == KITERS);
    if (tid < C_C) countsL[tid] = 0u;
    for (int i = tid; i < C_C * 8; i += 512) sums64[i] = 0ull;
    __syncthreads();

    // exact integer assignment
    for (int r = tid; r < L_Q; r += 512) {
      unsigned x = bitsL[r];
      unsigned best = 0xFFFFFFFFu;
#pragma unroll 8
      for (int c = 0; c < C_C; ++c) {
        unsigned d = (unsigned)__popc(x ^ centL[c]);
        unsigned key = (d << 8) | (unsigned)c;
        best = best < key ? best : key;
      }
      unsigned a = best & 0xFFu;
      assignL[r] = a;
      atomicAdd(&countsL[a], 1u);
    }
    __syncthreads();

    if (!last) {
      // bit sums (4 x 16-bit counters per u64)
      for (int r = tid; r < L_Q; r += 512) {
        unsigned a = assignL[r], w = bitsL[r];
#pragma unroll
        for (int g = 0; g < 8; ++g) {
          unsigned nib = (w >> (4*g)) & 0xFu;
          unsigned long long v = (unsigned long long)(nib & 1u)
            | ((unsigned long long)((nib >> 1) & 1u) << 16)
            | ((unsigned long long)((nib >> 2) & 1u) << 32)
            | ((unsigned long long)((nib >> 3) & 1u) << 48);
          atomicAdd(&sums64[a*8 + g], v);
        }
      }
      __syncthreads();
      // majority vote (2*sum > count), empty clusters keep old centroid
      if (tid < C_C) {
        unsigned cnt = countsL[tid];
        if (cnt > 0u) {
          unsigned wn = 0;
#pragma unroll
          for (int g = 0; g < 8; ++g) {
            unsigned long long s = sums64[tid*8 + g];
#pragma unroll
            for (int k2 = 0; k2 < 4; ++k2) {
              unsigned sc = (unsigned)((s >> (16*k2)) & 0xFFFFull);
              if (2u*sc > cnt) wn |= (1u << (4*g + k2));
            }
          }
          centL[tid] = wn;
        }
      }
      __syncthreads();
    }
  }

  // Qg accumulation (cluster means of Q), f32 output (no bf16 rounding)
  for (int i = tid; i < C_C * 65; i += 512) qgL[i] = 0.f;
  __syncthreads();
  int n = nh >> 3, h = nh & 7;
  for (int r = tid; r < L_Q; r += 512) {
    unsigned a = assignL[r];
    const float* qp = q + ((size_t)((size_t)(n * L_Q + r) * H_N + h)) * E_D;
    float* dst = &qgL[a * 65];
#pragma unroll
    for (int j = 0; j < 16; ++j) {
      f32x4 vq = *(const f32x4*)(qp + 4*j);
      atomicAdd(dst + 4*j + 0, vq[0]);
      atomicAdd(dst + 4*j + 1, vq[1]);
      atomicAdd(dst + 4*j + 2, vq[2]);
      atomicAdd(dst + 4*j + 3, vq[3]);
    }
  }
  __syncthreads();
  for (int i = tid; i < C_C * E_D; i += 512) {
    int c = i >> 6, d = i & 63;
    float cnt = (float)countsL[c]; if (cnt < 1.f) cnt = 1.f;
    qg_f32[(size_t)nh * C_C * E_D + i] = qgL[c*65 + d] / cnt;
  }
  for (int r = tid; r < L_Q; r += 512) assign_g[(size_t)nh * L_Q + r] = assignL[r];
}

// ---------------- kernel 3: exact f32 partial attention (control path) ----------------
// grid = NH*NCHUNK blocks, 256 threads; thread owns cluster c = tid.
// Qg row + O accumulator in registers; K/V rows broadcast from LDS.
// Online softmax in f32; partials (raw-max m, l, O) per chunk.
__global__ __launch_bounds__(256) void k_attn_f32(const float* __restrict__ keys,
                                                  const float* __restrict__ values,
                                                  const float* __restrict__ qg_f32,
                                                  float* __restrict__ part_m,
                                                  float* __restrict__ part_l,
                                                  float* __restrict__ part_O) {
  __shared__ float Ks[128][64];
  __shared__ float Vs[128][64];
  int tid = threadIdx.x;
  int nh = blockIdx.x >> 3, ch = blockIdx.x & 7;
  int n = nh >> 3, h = nh & 7;
  int s_base = ch * CHUNK;

  float qg[64];
  const float* qp = qg_f32 + ((size_t)nh * C_C + tid) * E_D;
#pragma unroll
  for (int j = 0; j < 16; ++j) {
    f32x4 v = *(const f32x4*)(qp + 4*j);
    qg[4*j+0] = v[0]; qg[4*j+1] = v[1]; qg[4*j+2] = v[2]; qg[4*j+3] = v[3];
  }

  float m = -1e30f, l = 0.f;
  float O[64];
#pragma unroll
  for (int d = 0; d < 64; ++d) O[d] = 0.f;

  for (int sub = 0; sub < CHUNK/128; ++sub) {
    __syncthreads();
    {
      int row = tid >> 1, half = tid & 1;
      size_t grow = ((size_t)(n * S_K + s_base + sub*128 + row) * H_N + h);
      const float* kp = keys   + grow * E_D + half*32;
      const float* vp = values + grow * D_V + half*32;
#pragma unroll
      for (int j = 0; j < 8; ++j) {
        *(f32x4*)&Ks[row][half*32 + 4*j] = *(const f32x4*)(kp + 4*j);
        *(f32x4*)&Vs[row][half*32 + 4*j] = *(const f32x4*)(vp + 4*j);
      }
    }
    __syncthreads();
    for (int s = 0; s < 128; ++s) {
      // dot(Qg_c, K_s) in f32 (4 partial chains for ILP; analog path, order-insensitive)
      float d0 = 0.f, d1 = 0.f, d2 = 0.f, d3 = 0.f;
#pragma unroll
      for (int j = 0; j < 16; ++j) {
        f32x4 kv = *(const f32x4*)&Ks[s][4*j];
        d0 = fmaf(qg[4*j+0], kv[0], d0);
        d1 = fmaf(qg[4*j+1], kv[1], d1);
        d2 = fmaf(qg[4*j+2], kv[2], d2);
        d3 = fmaf(qg[4*j+3], kv[3], d3);
      }
      float dot = (d0 + d1) + (d2 + d3);
      float mn = fmaxf(m, dot);
      if (mn > m) {
        float f = exp2f((m - mn) * TS_CONST);
        l *= f;
#pragma unroll
        for (int d = 0; d < 64; ++d) O[d] *= f;
        m = mn;
      }
      float p = exp2f((dot - m) * TS_CONST);
      l += p;
#pragma unroll
      for (int j = 0; j < 16; ++j) {
        f32x4 vv = *(const f32x4*)&Vs[s][4*j];
        O[4*j+0] = fmaf(p, vv[0], O[4*j+0]);
        O[4*j+1] = fmaf(p, vv[1], O[4*j+1]);
        O[4*j+2] = fmaf(p, vv[2], O[4*j+2]);
        O[4*j+3] = fmaf(p, vv[3], O[4*j+3]);
      }
    }
  }
  size_t base = (size_t)blockIdx.x * C_C + tid;
  part_m[base] = m;
  part_l[base] = l;
#pragma unroll
  for (int j = 0; j < 16; ++j) {
    f32x4 v = { O[4*j+0], O[4*j+1], O[4*j+2], O[4*j+3] };
    *(f32x4*)&part_O[base*64 + 4*j] = v;
  }
}

// ---------------- kernel 4: combine chunk partials ----------------
__global__ __launch_bounds__(256) void k_combine(const float* __restrict__ pm,
                                                 const float* __restrict__ pl_,
                                                 const float* __restrict__ pO,
                                                 float* __restrict__ Vc) {
  int id = blockIdx.x * 256 + threadIdx.x;       // 32*256*64
  int d = id & 63, c = (id >> 6) & 255, nh = id >> 14;
  float M = -1e30f;
#pragma unroll
  for (int ch = 0; ch < NCHUNK; ++ch)
    M = fmaxf(M, pm[((size_t)nh*NCHUNK + ch)*C_C + c]);
  float den = 0.f, num = 0.f;
#pragma unroll
  for (int ch = 0; ch < NCHUNK; ++ch) {
    size_t idx = ((size_t)nh*NCHUNK + ch)*C_C + c;
    float w = exp2f((pm[idx] - M) * TS_CONST);
    den += pl_[idx] * w;
    num += pO[idx*64 + d] * w;
  }
  Vc[((size_t)nh*C_C + c)*64 + d] = num / den;
}

// ---------------- kernel 5: gather ----------------
__global__ __launch_bounds__(256) void k_gather(const unsigned* __restrict__ assign_g,
                                                const float* __restrict__ Vc,
                                                float* __restrict__ out) {
  int id = blockIdx.x * 256 + threadIdx.x;       // N*L*H*16
  int dq = id & 15, h = (id >> 4) & 7, l = (id >> 7) & 4095, n = id >> 19;
  int nh = n*8 + h;
  unsigned a = assign_g[(size_t)nh * L_Q + l];
  f32x4 v = *(const f32x4*)&Vc[((size_t)nh*C_C + a)*64 + dq*4];
  *(f32x4*)&out[(size_t)id * 4] = v;
}

// ---------------- host ----------------
extern "C" void kernel_launch(void* const* d_in, const int* in_sizes, int n_in,
                              void* d_out, int out_size, void* d_ws, size_t ws_size,
                              hipStream_t stream) {
  (void)in_sizes; (void)n_in; (void)out_size; (void)ws_size;
  const float* q      = (const float*)d_in[0];
  const float* keys   = (const float*)d_in[1];
  const float* values = (const float*)d_in[2];
  const float* planes = (const float*)d_in[3];
  float* out = (float*)d_out;
  char* ws = (char*)d_ws;

  // pO (16MB @0) overlaps bits_g (512KB @0): safe by stream order —
  // bits_g is dead (fully consumed by k_cluster) before k_attn_f32 writes pO.
  float*     pO       = (float*)ws;                          // 16 MB @0
  unsigned*  bits_g   = (unsigned*)ws;                       // 512 KB @0 (dead before pO written)
  unsigned*  assign_g = (unsigned*)(ws + (16384u<<10));      // 512 KB @16MB
  float*     qg_f32   = (float*)(ws + (16896u<<10));         // 2 MB   @16.5MB
  float*     pm       = (float*)(ws + (18944u<<10));         // 256 KB @18.5MB
  float*     pl_      = (float*)(ws + (19200u<<10));         // 256 KB @18.75MB
  float*     Vc       = (float*)(ws + (19456u<<10));         // 2 MB   @19MB

  hipFuncSetAttribute((const void*)k_cluster, hipFuncAttributeMaxDynamicSharedMemorySize, 118784);

  k_bits<<<dim3(16, 32), 256, 0, stream>>>(q, planes, bits_g);
  k_cluster<<<32, 512, 118784, stream>>>(bits_g, q, assign_g, qg_f32);
  k_attn_f32<<<NH * NCHUNK, 256, 0, stream>>>(keys, values, qg_f32, pm, pl_, pO);
  k_combine<<<2048, 256, 0, stream>>>(pm, pl_, pO, Vc);
  k_gather<<<8192, 256, 0, stream>>>(assign_g, Vc, out);
}

// Round 6
// 928.802 us; speedup vs baseline: 1.3916x; 1.3916x over previous
//
#include <hip/hip_runtime.h>
#include <cstdint>
#include <cstddef>

// ---------------- problem constants ----------------
#define N_B   4
#define L_Q   4096
#define S_K   4096
#define H_N   8
#define E_D   64
#define D_V   64
#define C_C   256
#define NBITS 32
#define KITERS 10
#define NH    32            // N_B*H_N
#define NCHUNK 16
#define CHUNK  256          // keys per flash chunk

typedef __attribute__((ext_vector_type(4))) float f32x4;
typedef __attribute__((ext_vector_type(8))) short bf16x8;

#define TS_CONST (0.125f * 1.44269504088896340736f)   // softmax_temp * log2(e)

static __device__ __forceinline__ unsigned short f2bf(float x) {
  union { float f; unsigned u; } a; a.f = x;
  unsigned r = a.u + 0x7FFFu + ((a.u >> 16) & 1u);
  return (unsigned short)(r >> 16);
}

// build 8-element bf16 fragment from 8 bits (bit i -> element i); set-bit value
// given by lov (low half of u32) / hiv (high half), clear bit -> 0.0
static __device__ __forceinline__ bf16x8 frag8(unsigned tb, unsigned lov, unsigned hiv) {
  union { unsigned u[4]; bf16x8 v; } r;
#pragma unroll
  for (int j = 0; j < 4; ++j) {
    unsigned u = (((tb >> (2*j)) & 1u) ? lov : 0u) | (((tb >> (2*j+1)) & 1u) ? hiv : 0u);
    r.u[j] = u;
  }
  return r.v;
}

// ---------------- kernel 1: LSH bits ----------------
// thread per (nh,l); f64 accumulation (matches the f64 np reference to ~1e-13;
// sign-flip probability ~1e-9 per bit).
__global__ __launch_bounds__(256) void k_bits(const float* __restrict__ q,
                                              const float* __restrict__ planes,
                                              unsigned* __restrict__ bits_g) {
  __shared__ float pl[NBITS][E_D + 1];
  int tid = threadIdx.x;
  for (int i = tid; i < NBITS * (E_D + 1); i += 256) pl[i / (E_D+1)][i % (E_D+1)] = planes[i];
  __syncthreads();
  int l  = blockIdx.x * 256 + tid;
  int nh = blockIdx.y;
  int n = nh >> 3, h = nh & 7;
  const float* qp = q + ((size_t)((size_t)(n * L_Q + l) * H_N + h)) * E_D;
  float qv[E_D];
#pragma unroll
  for (int j = 0; j < E_D/4; ++j) {
    f32x4 v = *(const f32x4*)(qp + 4*j);
    qv[4*j+0] = v[0]; qv[4*j+1] = v[1]; qv[4*j+2] = v[2]; qv[4*j+3] = v[3];
  }
  unsigned w = 0;
#pragma unroll
  for (int half = 0; half < 2; ++half) {
    double acc[NBITS/2];
#pragma unroll
    for (int b = 0; b < NBITS/2; ++b) acc[b] = 0.0;
#pragma unroll 4
    for (int e = 0; e < E_D; ++e) {
      double qe = (double)qv[e];
#pragma unroll
      for (int b = 0; b < NBITS/2; ++b)
        acc[b] = fma(qe, (double)pl[half*(NBITS/2) + b][e], acc[b]);
    }
#pragma unroll
    for (int b = 0; b < NBITS/2; ++b) {
      double p = acc[b] + (double)pl[half*(NBITS/2) + b][E_D];
      if (p > 0.0) w |= (1u << (half*(NBITS/2) + b));
    }
  }
  bits_g[(size_t)nh * L_Q + l] = w;
}

// ---------------- kernel 2: Lloyd clustering + Qg ----------------
// one workgroup (512 thr) per nh. All state in (dynamic) LDS.
// Assignment via MFMA Hamming argmin (exact in f32, unique-key tie-break;
// empirically bit-identical to the integer (popc<<8)|c path, rounds 0 vs 1-4):
//   D[c,r] = popc(cent_c) + c*2^-12 - 2*dot(cent_c, x_r); min over c.
// LDS layout (bytes):
//   sums64 : 0      .. 16384   u64[256][8]  (4x16-bit packed bit counters)
//   bitsL  : 16384  .. 32768   u32[4096]
//   assignL: 32768  .. 49152   u32[4096]
//   centL  : 49152  .. 50176   u32[256]
//   initv  : 50176  .. 51200   f32[256]  = popc(cent)+c*2^-12
//   countsL: 51200  .. 52224   u32[256]
//   qgL    : 52224  .. 118784  f32[256][65]
__global__ __launch_bounds__(512) void k_cluster(const unsigned* __restrict__ bits_g,
                                                 const float* __restrict__ q,
                                                 unsigned* __restrict__ assign_g,
                                                 unsigned short* __restrict__ qg_bf) {
  extern __shared__ char smem[];
  unsigned long long* sums64 = (unsigned long long*)smem;
  unsigned* bitsL   = (unsigned*)(smem + 16384);
  unsigned* assignL = (unsigned*)(smem + 32768);
  unsigned* centL   = (unsigned*)(smem + 49152);
  float*    initv   = (float*)(smem + 50176);
  unsigned* countsL = (unsigned*)(smem + 51200);
  float*    qgL     = (float*)(smem + 52224);

  int tid = threadIdx.x, nh = blockIdx.x;
  int lane = tid & 63, wave = tid >> 6;
  int lo = lane & 15, hi = lane >> 4;

  for (int r = tid; r < L_Q; r += 512) bitsL[r] = bits_g[(size_t)nh * L_Q + r];
  __syncthreads();
  if (tid < C_C) {
    // np.linspace(0, 4095, 256) in FLOAT64 (ref=np), truncated:
    // idx[i] = floor(i*(16+1/17)) = 16*i + i/17 EXACTLY (f64 product error
    // k*2^-48 < half-ulp; endpoint 255 -> 4095 automatic). The f32 (jnp)
    // variant differs at 10 indices — that was the 4.6e-2 bug (rounds 0-4).
    centL[tid] = bitsL[tid * 16 + tid / 17];
  }
  __syncthreads();

  for (int it = 0; it <= KITERS; ++it) {
    bool last = (it == KITERS);
    if (tid < C_C) {
      unsigned cw = centL[tid];
      initv[tid]  = (float)__popc(cw) + (float)tid * 0.000244140625f;  // Sc + c*2^-12
      countsL[tid] = 0u;
    }
    for (int i = tid; i < C_C * 8; i += 512) sums64[i] = 0ull;
    __syncthreads();

    // per-wave prebuilt fragments (iteration-invariant)
    bf16x8 afr[16];     // A = -2*cent  (M=c rows)
    f32x4  cfr[16];     // C-init = Sc + eps_c for rows of each c-tile
#pragma unroll
    for (int t = 0; t < 16; ++t) {
      unsigned cw = centL[t*16 + lo];
      afr[t] = frag8((cw >> (hi*8)) & 0xFFu, 0xC000u, 0xC0000000u);
      cfr[t] = *(const f32x4*)&initv[t*16 + hi*4];
    }
    // assignment: D[c,r] = Sc + eps_c - 2*dot(cent_c, x_r); min over c.
    // All D values distinct (eps_c = c/4096) and exactly representable
    // (integer + c/4096 needs 19 bits) -> frac(min)*4096 == argmin c,
    // first-min tie-break identical to np.argmin.
    for (int p = wave; p < 256; p += 8) {
      int r0 = p * 16;
      unsigned wb = bitsL[r0 + lo];
      bf16x8 bfrag = frag8((wb >> (hi*8)) & 0xFFu, 0x3F80u, 0x3F800000u);
      float kmin = 1e30f;
#pragma unroll
      for (int t = 0; t < 16; ++t) {
        f32x4 d = __builtin_amdgcn_mfma_f32_16x16x32_bf16(afr[t], bfrag, cfr[t], 0, 0, 0);
        kmin = fminf(fminf(fminf(d[0], d[1]), fminf(d[2], d[3])), kmin);
      }
      kmin = fminf(kmin, __shfl_xor(kmin, 16));
      kmin = fminf(kmin, __shfl_xor(kmin, 32));
      if (lane < 16) {
        int c = (int)((kmin - floorf(kmin)) * 4096.0f + 0.5f);
        assignL[r0 + lane] = (unsigned)c;
        atomicAdd(&countsL[c], 1u);
      }
    }
    __syncthreads();

    if (!last) {
      // bit sums (4 x 16-bit counters per u64)
      for (int r = tid; r < L_Q; r += 512) {
        unsigned a = assignL[r], w = bitsL[r];
#pragma unroll
        for (int g = 0; g < 8; ++g) {
          unsigned nib = (w >> (4*g)) & 0xFu;
          unsigned long long v = (unsigned long long)(nib & 1u)
            | ((unsigned long long)((nib >> 1) & 1u) << 16)
            | ((unsigned long long)((nib >> 2) & 1u) << 32)
            | ((unsigned long long)((nib >> 3) & 1u) << 48);
          atomicAdd(&sums64[a*8 + g], v);
        }
      }
      __syncthreads();
      // majority vote (2*sum > count), empty clusters keep old centroid
      if (tid < C_C) {
        unsigned cnt = countsL[tid];
        if (cnt > 0u) {
          unsigned wn = 0;
#pragma unroll
          for (int g = 0; g < 8; ++g) {
            unsigned long long s = sums64[tid*8 + g];
#pragma unroll
            for (int k2 = 0; k2 < 4; ++k2) {
              unsigned sc = (unsigned)((s >> (16*k2)) & 0xFFFFull);
              if (2u*sc > cnt) wn |= (1u << (4*g + k2));
            }
          }
          centL[tid] = wn;
        }
      }
      __syncthreads();
    }
  }

  // Qg accumulation (cluster means of Q)
  for (int i = tid; i < C_C * 65; i += 512) qgL[i] = 0.f;
  __syncthreads();
  int n = nh >> 3, h = nh & 7;
  for (int r = tid; r < L_Q; r += 512) {
    unsigned a = assignL[r];
    const float* qp = q + ((size_t)((size_t)(n * L_Q + r) * H_N + h)) * E_D;
    float* dst = &qgL[a * 65];
#pragma unroll
    for (int j = 0; j < 16; ++j) {
      f32x4 vq = *(const f32x4*)(qp + 4*j);
      atomicAdd(dst + 4*j + 0, vq[0]);
      atomicAdd(dst + 4*j + 1, vq[1]);
      atomicAdd(dst + 4*j + 2, vq[2]);
      atomicAdd(dst + 4*j + 3, vq[3]);
    }
  }
  __syncthreads();
  for (int i = tid; i < C_C * E_D; i += 512) {
    int c = i >> 6, d = i & 63;
    float cnt = (float)countsL[c]; if (cnt < 1.f) cnt = 1.f;
    qg_bf[(size_t)nh * C_C * E_D + i] = f2bf(qgL[c*65 + d] / cnt);
  }
  for (int r = tid; r < L_Q; r += 512) assign_g[(size_t)nh * L_Q + r] = assignL[r];
}

// ---------------- kernel 3: flash partial attention (bf16 MFMA) ----------------
// grid = nh*16 chunks, block 256 (4 waves), 256 keys/chunk, 2-pass softmax.
// LDS: Kl [256][72] u16 @0 ; Vt [64][264] u16 @36864 ; Pl [4][64][40] u16 @70656
__global__ __launch_bounds__(256) void k_flash(const float* __restrict__ keys,
                                               const float* __restrict__ values,
                                               const unsigned short* __restrict__ qg_bf,
                                               float* __restrict__ part_m,
                                               float* __restrict__ part_l,
                                               float* __restrict__ part_O) {
  extern __shared__ char smem[];
  unsigned short* Kl = (unsigned short*)smem;
  unsigned short* Vt = (unsigned short*)(smem + 36864);
  unsigned short* Pl = (unsigned short*)(smem + 70656);

  int tid = threadIdx.x, lane = tid & 63, wave = tid >> 6;
  int lo = lane & 15, hi2 = lane >> 4;
  int nh = blockIdx.x >> 4, ch = blockIdx.x & 15;
  int n = nh >> 3, h = nh & 7;
  int s_base = ch * CHUNK;

  // stage K (row-major bf16) and V (transposed bf16) into LDS
  for (int blk = 0; blk < 8; ++blk) {
    int sr = blk*32 + (tid >> 3), eb = tid & 7;
    size_t grow = ((size_t)(n * S_K + s_base + sr) * H_N + h);
    const float* kp = keys   + grow * E_D + eb*8;
    const float* vp = values + grow * D_V + eb*8;
    f32x4 ka = *(const f32x4*)kp; f32x4 kb = *(const f32x4*)(kp + 4);
    union { unsigned short s[8]; bf16x8 v; } ku;
    ku.s[0]=f2bf(ka[0]); ku.s[1]=f2bf(ka[1]); ku.s[2]=f2bf(ka[2]); ku.s[3]=f2bf(ka[3]);
    ku.s[4]=f2bf(kb[0]); ku.s[5]=f2bf(kb[1]); ku.s[6]=f2bf(kb[2]); ku.s[7]=f2bf(kb[3]);
    *(bf16x8*)&Kl[sr*72 + eb*8] = ku.v;
    f32x4 va = *(const f32x4*)vp; f32x4 vb4 = *(const f32x4*)(vp + 4);
    float vv[8] = {va[0],va[1],va[2],va[3],vb4[0],vb4[1],vb4[2],vb4[3]};
#pragma unroll
    for (int jj = 0; jj < 8; ++jj) {
      int j = (jj + eb) & 7;                       // rotate to spread LDS banks
      Vt[(eb*8 + j)*264 + sr] = f2bf(vv[j]);
    }
  }
  __syncthreads();

  // Qg B-fragments (col c = lo, k = hi2*8 + i + 32*kf)
  bf16x8 qf[4][2];
#pragma unroll
  for (int ct = 0; ct < 4; ++ct)
#pragma unroll
    for (int kf = 0; kf < 2; ++kf)
      qf[ct][kf] = *(const bf16x8*)(qg_bf + ((size_t)nh*C_C + (wave*64 + ct*16 + lo))*E_D + kf*32 + hi2*8);

  f32x4 zero4 = {0.f, 0.f, 0.f, 0.f};

  // pass 1: per-column raw-logit max over the chunk
  float mrun[4] = {-1e30f, -1e30f, -1e30f, -1e30f};
  for (int st = 0; st < 8; ++st) {
#pragma unroll
    for (int sub = 0; sub < 2; ++sub) {
      int srow = st*32 + sub*16 + lo;
      bf16x8 a0 = *(const bf16x8*)&Kl[srow*72 + hi2*8];
      bf16x8 a1 = *(const bf16x8*)&Kl[srow*72 + 32 + hi2*8];
#pragma unroll
      for (int ct = 0; ct < 4; ++ct) {
        f32x4 acc = __builtin_amdgcn_mfma_f32_16x16x32_bf16(a0, qf[ct][0], zero4, 0, 0, 0);
        acc = __builtin_amdgcn_mfma_f32_16x16x32_bf16(a1, qf[ct][1], acc, 0, 0, 0);
        mrun[ct] = fmaxf(mrun[ct], fmaxf(fmaxf(acc[0], acc[1]), fmaxf(acc[2], acc[3])));
      }
    }
  }
#pragma unroll
  for (int ct = 0; ct < 4; ++ct) {
    mrun[ct] = fmaxf(mrun[ct], __shfl_xor(mrun[ct], 16));
    mrun[ct] = fmaxf(mrun[ct], __shfl_xor(mrun[ct], 32));
  }

  // pass 2: exp + l-sum + PV
  float lrun[4] = {0.f, 0.f, 0.f, 0.f};
  f32x4 oacc[4][4];
#pragma unroll
  for (int mt = 0; mt < 4; ++mt)
#pragma unroll
    for (int nt = 0; nt < 4; ++nt) oacc[mt][nt] = zero4;

  for (int st = 0; st < 8; ++st) {
#pragma unroll
    for (int sub = 0; sub < 2; ++sub) {
      int srow = st*32 + sub*16 + lo;
      bf16x8 a0 = *(const bf16x8*)&Kl[srow*72 + hi2*8];
      bf16x8 a1 = *(const bf16x8*)&Kl[srow*72 + 32 + hi2*8];
#pragma unroll
      for (int ct = 0; ct < 4; ++ct) {
        f32x4 acc = __builtin_amdgcn_mfma_f32_16x16x32_bf16(a0, qf[ct][0], zero4, 0, 0, 0);
        acc = __builtin_amdgcn_mfma_f32_16x16x32_bf16(a1, qf[ct][1], acc, 0, 0, 0);
        float p0 = exp2f((acc[0] - mrun[ct]) * TS_CONST);
        float p1 = exp2f((acc[1] - mrun[ct]) * TS_CONST);
        float p2 = exp2f((acc[2] - mrun[ct]) * TS_CONST);
        float p3 = exp2f((acc[3] - mrun[ct]) * TS_CONST);
        lrun[ct] += (p0 + p1) + (p2 + p3);
        unsigned u01 = (unsigned)f2bf(p0) | ((unsigned)f2bf(p1) << 16);
        unsigned u23 = (unsigned)f2bf(p2) | ((unsigned)f2bf(p3) << 16);
        unsigned short* pw = &Pl[wave*2560 + (ct*16 + lo)*40 + sub*16 + hi2*4];
        *(unsigned*)(pw)     = u01;
        *(unsigned*)(pw + 2) = u23;
      }
    }
    // PV: O[c,d] += P^T[c,s] * V[s,d]   (same-wave in-order LDS: no barrier needed)
    bf16x8 vb[4];
#pragma unroll
    for (int nt = 0; nt < 4; ++nt)
      vb[nt] = *(const bf16x8*)&Vt[(nt*16 + lo)*264 + st*32 + hi2*8];
#pragma unroll
    for (int mt = 0; mt < 4; ++mt) {
      bf16x8 pa = *(const bf16x8*)&Pl[wave*2560 + (mt*16 + lo)*40 + hi2*8];
#pragma unroll
      for (int nt = 0; nt < 4; ++nt)
        oacc[mt][nt] = __builtin_amdgcn_mfma_f32_16x16x32_bf16(pa, vb[nt], oacc[mt][nt], 0, 0, 0);
    }
  }
#pragma unroll
  for (int ct = 0; ct < 4; ++ct) {
    lrun[ct] += __shfl_xor(lrun[ct], 16);
    lrun[ct] += __shfl_xor(lrun[ct], 32);
  }
  size_t base = (size_t)blockIdx.x * C_C;
  if (lane < 16) {
#pragma unroll
    for (int ct = 0; ct < 4; ++ct) {
      int c = wave*64 + ct*16 + lane;
      part_m[base + c] = mrun[ct];
      part_l[base + c] = lrun[ct];
    }
  }
#pragma unroll
  for (int mt = 0; mt < 4; ++mt)
#pragma unroll
    for (int nt = 0; nt < 4; ++nt)
#pragma unroll
      for (int rg = 0; rg < 4; ++rg) {
        int c = wave*64 + mt*16 + hi2*4 + rg;
        int d = nt*16 + lo;
        part_O[(base + c)*64 + d] = oacc[mt][nt][rg];
      }
}

// ---------------- kernel 4: combine chunk partials ----------------
__global__ __launch_bounds__(256) void k_combine(const float* __restrict__ pm,
                                                 const float* __restrict__ pl_,
                                                 const float* __restrict__ pO,
                                                 float* __restrict__ Vc) {
  int id = blockIdx.x * 256 + threadIdx.x;       // 32*256*64
  int d = id & 63, c = (id >> 6) & 255, nh = id >> 14;
  float M = -1e30f;
#pragma unroll
  for (int ch = 0; ch < NCHUNK; ++ch)
    M = fmaxf(M, pm[((size_t)nh*NCHUNK + ch)*C_C + c]);
  float den = 0.f, num = 0.f;
#pragma unroll
  for (int ch = 0; ch < NCHUNK; ++ch) {
    size_t idx = ((size_t)nh*NCHUNK + ch)*C_C + c;
    float w = exp2f((pm[idx] - M) * TS_CONST);
    den += pl_[idx] * w;
    num += pO[idx*64 + d] * w;
  }
  Vc[((size_t)nh*C_C + c)*64 + d] = num / den;
}

// ---------------- kernel 5: gather ----------------
__global__ __launch_bounds__(256) void k_gather(const unsigned* __restrict__ assign_g,
                                                const float* __restrict__ Vc,
                                                float* __restrict__ out) {
  int id = blockIdx.x * 256 + threadIdx.x;       // N*L*H*16
  int dq = id & 15, h = (id >> 4) & 7, l = (id >> 7) & 4095, n = id >> 19;
  int nh = n*8 + h;
  unsigned a = assign_g[(size_t)nh * L_Q + l];
  f32x4 v = *(const f32x4*)&Vc[((size_t)nh*C_C + a)*64 + dq*4];
  *(f32x4*)&out[(size_t)id * 4] = v;
}

// ---------------- host ----------------
extern "C" void kernel_launch(void* const* d_in, const int* in_sizes, int n_in,
                              void* d_out, int out_size, void* d_ws, size_t ws_size,
                              hipStream_t stream) {
  (void)in_sizes; (void)n_in; (void)out_size; (void)ws_size;
  const float* q      = (const float*)d_in[0];
  const float* keys   = (const float*)d_in[1];
  const float* values = (const float*)d_in[2];
  const float* planes = (const float*)d_in[3];
  float* out = (float*)d_out;
  char* ws = (char*)d_ws;

  unsigned*        bits_g   = (unsigned*)ws;                               // 512 KB
  unsigned*        assign_g = (unsigned*)(ws + (512u<<10));                // 512 KB
  unsigned short*  qg_bf    = (unsigned short*)(ws + (1024u<<10));         // 1 MB
  float*           pm       = (float*)(ws + (2048u<<10));                  // 512 KB
  float*           pl_      = (float*)(ws + (2560u<<10));                  // 512 KB
  float*           Vc       = (float*)(ws + (3072u<<10));                  // 2 MB
  float*           pO       = (float*)(ws + (5120u<<10));                  // 32 MB

  hipFuncSetAttribute((const void*)k_cluster, hipFuncAttributeMaxDynamicSharedMemorySize, 118784);
  hipFuncSetAttribute((const void*)k_flash,   hipFuncAttributeMaxDynamicSharedMemorySize, 91136);

  k_bits<<<dim3(16, 32), 256, 0, stream>>>(q, planes, bits_g);
  k_cluster<<<32, 512, 118784, stream>>>(bits_g, q, assign_g, qg_bf);
  k_flash<<<512, 256, 91136, stream>>>(keys, values, qg_bf, pm, pl_, pO);
  k_combine<<<2048, 256, 0, stream>>>(pm, pl_, pO, Vc);
  k_gather<<<8192, 256, 0, stream>>>(assign_g, Vc, out);
}